// Round 8
// baseline (218.946 us; speedup 1.0000x reference)
//
#include <hip/hip_runtime.h>
#include <math.h>

#define B_ 4
#define L_ 4096
#define D_ 256
#define A_ 64
#define M_ (B_*L_)   // 16384 flat rows

typedef _Float16 half4 __attribute__((ext_vector_type(4)));
typedef _Float16 half8 __attribute__((ext_vector_type(8)));
typedef __attribute__((ext_vector_type(4))) float floatx4;

__device__ __forceinline__ unsigned short f2h_(float f) {
    _Float16 h = (_Float16)f;
    return __builtin_bit_cast(unsigned short, h);
}

// ---------------------------------------------------------------------------
// wconv: W f32 [256][64] -> W^T fp16 [64][256]. Wq scaled by 1/ln2 (exp2
// softmax domain). grid (3), block 256.
// ---------------------------------------------------------------------------
__global__ __launch_bounds__(256) void wconv_kernel(
    const float* __restrict__ Wq, const float* __restrict__ Wk,
    const float* __restrict__ Wv, unsigned short* __restrict__ wt)
{
    const int w = blockIdx.x, t = threadIdx.x;
    const float* W = (w == 0) ? Wq : (w == 1) ? Wk : Wv;
    unsigned short* o = wt + w * A_ * D_;
    const float scale = (w == 0) ? 1.44269504f : 1.0f;
    __shared__ float T[A_ * 260];
    #pragma unroll
    for (int p = 0; p < 16; ++p) {
        int idx = p * 256 + t;
        int d = idx >> 4, a4 = (idx & 15) * 4;
        float4 v = *(const float4*)(W + d * A_ + a4);
        T[(a4 + 0) * 260 + d] = v.x * scale;
        T[(a4 + 1) * 260 + d] = v.y * scale;
        T[(a4 + 2) * 260 + d] = v.z * scale;
        T[(a4 + 3) * 260 + d] = v.w * scale;
    }
    __syncthreads();
    const int a = t >> 2, d0 = (t & 3) * 64;
    #pragma unroll
    for (int i = 0; i < 16; ++i) {
        float4 v = *(const float4*)(&T[a * 260 + d0 + 4 * i]);
        ushort4 s;
        s.x = f2h_(v.x); s.y = f2h_(v.y); s.z = f2h_(v.z); s.w = f2h_(v.w);
        *(ushort4*)(o + a * D_ + d0 + 4 * i) = s;
    }
}

// ---------------------------------------------------------------------------
// proj: one block per 32 x-rows computes ALL 3 projections (x staged once).
// grid (M/32), block 384 = 6 waves: wave = (w = wid>>1, mt = wid&1).
// q/k fp16 [M][64]; v fp16 TRANSPOSED [B][64][L].
// ---------------------------------------------------------------------------
__global__ __launch_bounds__(384) void proj_kernel(
    const float* __restrict__ x,           // [M][256] f32
    const unsigned short* __restrict__ wt, // [3][64][256] fp16 (W^T)
    unsigned short* __restrict__ qo,
    unsigned short* __restrict__ ko,
    unsigned short* __restrict__ vto)
{
    __shared__ __align__(16) unsigned short Xh[32 * 264];   // 16.5 KB
    __shared__ __align__(16) unsigned short Cst[6 * 1536];  // 18 KB
    const int t = threadIdx.x, m0 = blockIdx.x * 32;

    #pragma unroll
    for (int p = 0; p < 6; ++p) {
        int idx = p * 384 + t;
        if (idx < 2048) {
            int row = idx >> 6, col = (idx & 63) * 4;
            float4 v = *(const float4*)(x + (size_t)(m0 + row) * D_ + col);
            ushort4 s;
            s.x = f2h_(v.x); s.y = f2h_(v.y); s.z = f2h_(v.z); s.w = f2h_(v.w);
            *(ushort4*)(Xh + row * 264 + col) = s;
        }
    }
    __syncthreads();

    const int wid = t >> 6, lane = t & 63, c = lane & 15, g = lane >> 4;
    const int w = wid >> 1, mt = wid & 1;

    half8 xa[8];
    #pragma unroll
    for (int s = 0; s < 8; ++s)
        xa[s] = *(const half8*)(Xh + (16 * mt + c) * 264 + 32 * s + 8 * g);

    const unsigned short* wsrc = wt + w * A_ * D_;
    unsigned short* Cw = Cst + wid * 1536;
    #pragma unroll
    for (int nt = 0; nt < 4; ++nt) {
        floatx4 acc = {0.f, 0.f, 0.f, 0.f};
        #pragma unroll
        for (int s = 0; s < 8; ++s) {
            half8 wb = *(const half8*)(wsrc + (16 * nt + c) * D_ + 32 * s + 8 * g);
            acc = __builtin_amdgcn_mfma_f32_16x16x32_f16(xa[s], wb, acc, 0, 0, 0);
        }
        if (w < 2) {
            #pragma unroll
            for (int r = 0; r < 4; ++r)
                Cw[(4 * g + r) * 72 + 16 * nt + c] = f2h_(acc[r]);      // [m16][72]
        } else {
            #pragma unroll
            for (int r = 0; r < 4; ++r)
                Cw[(16 * nt + c) * 24 + 4 * g + r] = f2h_(acc[r]);      // [a64][24]
        }
    }

    if (w < 2) {
        unsigned short* o = (w == 0) ? qo : ko;
        const int row16 = lane >> 2, seg = lane & 3;
        uint4 d0 = *(const uint4*)(Cw + row16 * 72 + seg * 16);
        uint4 d1 = *(const uint4*)(Cw + row16 * 72 + seg * 16 + 8);
        unsigned short* p = o + (size_t)(m0 + 16 * mt + row16) * A_ + seg * 16;
        *(uint4*)(p) = d0;
        *(uint4*)(p + 8) = d1;
    }
    __syncthreads();
    if (t < 256) {
        const int a = t >> 2, quarter = t & 3;
        const int o = quarter * 8, mtv = o >> 4, idx = o & 15;
        uint4 d = *(const uint4*)(Cst + (4 + mtv) * 1536 + a * 24 + idx);
        const int bb = m0 >> 12, l0 = m0 & (L_ - 1);
        *(uint4*)(vto + ((size_t)(bb * A_ + a)) * L_ + l0 + o) = d;
    }
}

// ---------------------------------------------------------------------------
// attn: split-K flash, 128-q blocks, uniform chunks, BARRIER-FREE STREAMING.
// grid (576) 1D, block 512 = 8 waves = 4 qsub x 2 ph.
//
// R2/R6/R7 (three different LDS-staged barrier structures) all landed at the
// same total: the __syncthreads convoy was the invariant, not the staging
// engine. This version has NO LDS and NO barriers in the main loop: D=64
// lets K fragments (16B/lane, rows 128B-contiguous) and V^T fragments
// (8B/lane) feed MFMA directly from L2 (working set 2 MB/XCD, L2-resident).
// Each wave is an independent dataflow chain; the compiler software-
// pipelines the affine loads across iterations (nothing to hoist past),
// and 16 unsynchronized waves/CU hide L2 latency. L2 read amplification
// (4 waves/tile re-read K; V in 32B granules) ~400 MB ≈ 12 us device-wide,
// paid for by removing the per-iteration vmcnt(0)+barrier drain.
//
// Exact defer-max: when __all(tm <= m) skip the m-update and O-rescale
// entirely (al==1 exactly; no approximation).
//
// LDS only for the epilogue ph-pair combine (33 KB).
// Decomposition (unchanged): per batch 32 q-tiles, T = 2qt+2 key tiles,
// nch = ceil(T/8) chunks, 144/batch, big chunks first; x=bx&7 -> XCD,
// b=x>>1. Emits UNNORMALIZED (O,m,l) per chunk j: poB[j][M][64], mlB[j][M].
// ---------------------------------------------------------------------------
__global__ __launch_bounds__(512, 4) void attn_kernel(
    const unsigned short* __restrict__ qb,  // [B][L][64] fp16 (x 1/ln2)
    const unsigned short* __restrict__ kb,  // [B][L][64] fp16
    const unsigned short* __restrict__ vt,  // [B][64][L] fp16
    float* __restrict__ poB,                // [8][M][64] partial O
    float2* __restrict__ mlB)               // [8][M] (m,l)
{
    __shared__ __align__(16) float Of[8 * 1024];   // 32 KB epilogue buffer
    __shared__ float2 mlb[128];                    // 1 KB

    const int t    = threadIdx.x;
    const int lane = t & 63;
    const int wid  = t >> 6;          // 0..7
    const int qsub = wid >> 1;        // 0..3 -> 32-row group
    const int ph   = wid & 1;
    const int c    = lane & 15;
    const int g    = lane >> 4;

    // ---- block id -> (b, qt, chunk j of nch) ----
    const int bx = blockIdx.x;
    const int x  = bx & 7, u = bx >> 3;
    const int b  = x >> 1;
    const int gch = 143 - (2 * u + (x & 1));    // reversed: big chunks first
    int m = 0;
    while (2 * (m + 1) * (m + 2) <= gch) ++m;   // uniform scalar, <=7 iters
    const int rem = gch - 2 * m * (m + 1);
    const int nch = m + 1;
    const int qt  = 4 * m + rem / nch;
    const int j   = rem % nch;
    const int T   = 2 * qt + 2;
    const int t0  = (j * T) / nch;
    const int t1  = ((j + 1) * T) / nch;
    const int Tm2 = T - 2;

    const int q0    = qt * 128;
    const int qrow0 = q0 + 32 * qsub;
    const int qme0  = qrow0 + c;

    const size_t base  = (size_t)b * L_ * A_;
    const size_t vbase = (size_t)b * A_ * L_;

    half8 qf[2][2];
    #pragma unroll
    for (int f = 0; f < 2; ++f) {
        const unsigned short* qp = qb + base + (size_t)(qrow0 + 16 * f + c) * A_ + g * 8;
        qf[f][0] = *(const half8*)(qp);
        qf[f][1] = *(const half8*)(qp + 32);
    }

    floatx4 O4[2][4];
    #pragma unroll
    for (int f = 0; f < 2; ++f)
        #pragma unroll
        for (int at = 0; at < 4; ++at) O4[f][at] = (floatx4){0.f, 0.f, 0.f, 0.f};
    float m_[2] = {-INFINITY, -INFINITY};
    float l_[2] = {0.f, 0.f};

    // ---- barrier-free main loop: each wave streams its own tiles ----
    for (int kt = t0 + ph; kt < t1; kt += 2) {
        const unsigned short* Kp = kb + base + (size_t)(kt << 6) * 64;
        const unsigned short* Vp = vt + vbase + (kt << 6);
        const int k0 = kt << 6;

        half4 pf[2][4];
        #pragma unroll
        for (int f = 0; f < 2; ++f) {
            // ---- S^T = K . Q^T (frag f), K streamed from L2 ----
            floatx4 S4[4];
            #pragma unroll
            for (int nt = 0; nt < 4; ++nt) S4[nt] = (floatx4){0.f, 0.f, 0.f, 0.f};
            #pragma unroll
            for (int s = 0; s < 2; ++s)
                #pragma unroll
                for (int nt = 0; nt < 4; ++nt) {
                    half8 kf = *(const half8*)(Kp + (16 * nt + c) * 64 + s * 32 + g * 8);
                    S4[nt] = __builtin_amdgcn_mfma_f32_16x16x32_f16(kf, qf[f][s], S4[nt], 0, 0, 0);
                }

            // ---- causal mask: tiles >= T-2 straddle the 128-q diagonal ----
            if (kt >= Tm2) {
                const int qme = qme0 + 16 * f;
                #pragma unroll
                for (int nt = 0; nt < 4; ++nt)
                    #pragma unroll
                    for (int r = 0; r < 4; ++r)
                        if (k0 + 16 * nt + 4 * g + r > qme) S4[nt][r] = -INFINITY;
            }

            // ---- online softmax (exp2 domain; per-lane q row) ----
            float tm = fmaxf(fmaxf(fmaxf(S4[0][0], S4[0][1]), fmaxf(S4[0][2], S4[0][3])),
                             fmaxf(fmaxf(S4[1][0], S4[1][1]), fmaxf(S4[1][2], S4[1][3])));
            tm = fmaxf(tm, fmaxf(fmaxf(fmaxf(S4[2][0], S4[2][1]), fmaxf(S4[2][2], S4[2][3])),
                                 fmaxf(fmaxf(S4[3][0], S4[3][1]), fmaxf(S4[3][2], S4[3][3]))));
            tm = fmaxf(tm, __shfl_xor(tm, 16));
            tm = fmaxf(tm, __shfl_xor(tm, 32));

            float mnc;
            if (__all(tm <= m_[f])) {
                // exact defer: max unchanged for all 16 rows -> al == 1,
                // skip m-update and O-rescale entirely
                mnc = fmaxf(m_[f], -3.0e38f);
            } else {
                const float mn = fmaxf(m_[f], tm);
                mnc = fmaxf(mn, -3.0e38f);
                const float al = exp2f(fminf(m_[f] - mnc, 0.f));
                l_[f] *= al;
                m_[f] = mn;
                #pragma unroll
                for (int at = 0; at < 4; ++at) O4[f][at] *= al;
            }
            float rs = 0.f;
            #pragma unroll
            for (int nt = 0; nt < 4; ++nt) {
                #pragma unroll
                for (int r = 0; r < 4; ++r) {
                    float p = exp2f(S4[nt][r] - mnc);   // masked: exp2(-inf)=0
                    S4[nt][r] = p;
                    rs += p;
                }
                pf[f][nt][0] = (_Float16)S4[nt][0];
                pf[f][nt][1] = (_Float16)S4[nt][1];
                pf[f][nt][2] = (_Float16)S4[nt][2];
                pf[f][nt][3] = (_Float16)S4[nt][3];
            }
            rs += __shfl_xor(rs, 16);
            rs += __shfl_xor(rs, 32);
            l_[f] += rs;
        }

        // ---- O^T += V^T . P^T: V^T streamed from L2, feeds both frags ----
        #pragma unroll
        for (int at = 0; at < 4; ++at) {
            #pragma unroll
            for (int nt = 0; nt < 4; ++nt) {
                half4 va = *(const half4*)(Vp + (size_t)(16 * at + c) * L_ + 16 * nt + 4 * g);
                O4[0][at] = __builtin_amdgcn_mfma_f32_16x16x16f16(va, pf[0][nt], O4[0][at], 0, 0, 0);
                O4[1][at] = __builtin_amdgcn_mfma_f32_16x16x16f16(va, pf[1][nt], O4[1][at], 0, 0, 0);
            }
        }
    }

    // ---- epilogue: 2 passes (one per frag), combine ph pairs via LDS ----
    #pragma unroll
    for (int f = 0; f < 2; ++f) {
        __syncthreads();
        #pragma unroll
        for (int at = 0; at < 4; ++at) {
            float4 v; v.x = O4[f][at][0]; v.y = O4[f][at][1];
            v.z = O4[f][at][2]; v.w = O4[f][at][3];
            ((float4*)Of)[wid * 256 + at * 64 + lane] = v;
        }
        if (g == 0) { float2 ml; ml.x = m_[f]; ml.y = l_[f]; mlb[wid * 16 + c] = ml; }
        __syncthreads();

        const int q64 = t >> 3, seg = t & 7;
        const int qs = q64 >> 4, cc = q64 & 15;
        const int rowq = 32 * qs + 16 * f + cc;
        const float2 A0 = mlb[(2 * qs) * 16 + cc];
        const float2 A1 = mlb[(2 * qs + 1) * 16 + cc];
        const float mf = fmaxf(A0.x, A1.x);
        const float mc = fmaxf(mf, -3.0e38f);
        const float w0 = exp2f(A0.x - mc);
        const float w1 = exp2f(A1.x - mc);
        const float ls = w0 * A0.y + w1 * A1.y;
        float res[8];
        #pragma unroll
        for (int u2 = 0; u2 < 8; ++u2) {
            const int a = seg * 8 + u2;
            const int at = a >> 4, gg = (a >> 2) & 3, r = a & 3;
            const int i0 = ((2 * qs) * 256 + at * 64 + gg * 16 + cc) * 4 + r;
            const int i1 = ((2 * qs + 1) * 256 + at * 64 + gg * 16 + cc) * 4 + r;
            res[u2] = w0 * Of[i0] + w1 * Of[i1];
        }
        float* p = poB + (size_t)j * M_ * A_ + base + (size_t)(q0 + rowq) * A_ + seg * 8;
        *(float4*)(p)     = make_float4(res[0], res[1], res[2], res[3]);
        *(float4*)(p + 4) = make_float4(res[4], res[5], res[6], res[7]);
        if (seg == 0) {
            float2 ml; ml.x = mf; ml.y = ls;
            mlB[(size_t)j * M_ + b * L_ + q0 + rowq] = ml;
        }
    }
}

// ---------------------------------------------------------------------------
// merge: final = sum_j(Oj*wj) / sum_j(lj*wj) over nch(qt) chunks, computed
// ONLINE with a statically-unrolled predicated loop (no runtime-indexed
// array -> no scratch). grid (1024), block 256.
// ---------------------------------------------------------------------------
__global__ __launch_bounds__(256) void merge_kernel(
    float* __restrict__ out, const float* __restrict__ poB,
    const float2* __restrict__ mlB)
{
    const int tg = blockIdx.x * 256 + threadIdx.x;   // 262144 float4s
    const int q = tg >> 4;
    const int qt = (q & (L_ - 1)) >> 7;              // 128-row q-tiles
    const int nch = (qt + 4) >> 2;                   // ceil((2qt+2)/8)
    float mf = -INFINITY, den = 0.f;
    float4 acc = make_float4(0.f, 0.f, 0.f, 0.f);
    #pragma unroll
    for (int jj = 0; jj < 8; ++jj) {
        if (jj < nch) {
            const float2 aj = mlB[(size_t)jj * M_ + q];
            const float mn = fmaxf(mf, aj.x);
            const float mc = fmaxf(mn, -3.0e38f);
            const float sc = exp2f(fminf(mf - mc, 0.f));
            const float wj = exp2f(aj.x - mc);
            const float4 o = ((const float4*)(poB + (size_t)jj * M_ * A_))[tg];
            acc.x = acc.x * sc + o.x * wj;
            acc.y = acc.y * sc + o.y * wj;
            acc.z = acc.z * sc + o.z * wj;
            acc.w = acc.w * sc + o.w * wj;
            den = den * sc + aj.y * wj;
            mf = mn;
        }
    }
    const float inv = 1.f / den;
    float4 r;
    r.x = acc.x * inv; r.y = acc.y * inv; r.z = acc.z * inv; r.w = acc.w * inv;
    ((float4*)out)[tg] = r;
}

// ---------------------------------------------------------------------------
extern "C" void kernel_launch(void* const* d_in, const int* in_sizes, int n_in,
                              void* d_out, int out_size, void* d_ws, size_t ws_size,
                              hipStream_t stream) {
    const float* x  = (const float*)d_in[0];
    const float* Wq = (const float*)d_in[1];
    const float* Wk = (const float*)d_in[2];
    const float* Wv = (const float*)d_in[3];

    char* ws = (char*)d_ws;
    unsigned short* qb = (unsigned short*)(ws);                    // 2 MB
    unsigned short* kb = (unsigned short*)(ws + (2u << 20));       // 2 MB
    unsigned short* vt = (unsigned short*)(ws + (4u << 20));       // 2 MB
    unsigned short* wt = (unsigned short*)(ws + (6u << 20));       // 96 KB (128 KB reserved)
    char* p0 = ws + (6u << 20) + (128u << 10);
    float*  poB = (float*)(p0);                                    // 8 x 4 MB
    float2* mlB = (float2*)(p0 + (32u << 20));                     // 8 x 128 KB
    float* out = (float*)d_out;

    hipLaunchKernelGGL(wconv_kernel, dim3(3), dim3(256), 0, stream, Wq, Wk, Wv, wt);
    hipLaunchKernelGGL(proj_kernel, dim3(M_ / 32), dim3(384), 0, stream, x, wt, qb, kb, vt);
    hipLaunchKernelGGL(attn_kernel, dim3(576), dim3(512), 0, stream,
                       qb, kb, vt, poB, mlB);
    hipLaunchKernelGGL(merge_kernel, dim3(1024), dim3(256), 0, stream,
                       out, poB, mlB);
}

// Round 9
// 125.135 us; speedup vs baseline: 1.7497x; 1.7497x over previous
//
#include <hip/hip_runtime.h>
#include <math.h>

#define B_ 4
#define L_ 4096
#define D_ 256
#define A_ 64
#define M_ (B_*L_)   // 16384 flat rows

typedef _Float16 half4 __attribute__((ext_vector_type(4)));
typedef _Float16 half8 __attribute__((ext_vector_type(8)));
typedef __attribute__((ext_vector_type(4))) float floatx4;

__device__ __forceinline__ unsigned short f2h_(float f) {
    _Float16 h = (_Float16)f;
    return __builtin_bit_cast(unsigned short, h);
}
__device__ __forceinline__ unsigned int pack2_(float a, float b) {
    return (unsigned int)f2h_(a) | ((unsigned int)f2h_(b) << 16);
}

// ---------------------------------------------------------------------------
// wconv: W f32 [256][64] -> W^T fp16 [64][256]. Wq scaled by 1/ln2 (exp2
// softmax domain). grid (3), block 256.
// ---------------------------------------------------------------------------
__global__ __launch_bounds__(256) void wconv_kernel(
    const float* __restrict__ Wq, const float* __restrict__ Wk,
    const float* __restrict__ Wv, unsigned short* __restrict__ wt)
{
    const int w = blockIdx.x, t = threadIdx.x;
    const float* W = (w == 0) ? Wq : (w == 1) ? Wk : Wv;
    unsigned short* o = wt + w * A_ * D_;
    const float scale = (w == 0) ? 1.44269504f : 1.0f;
    __shared__ float T[A_ * 260];
    #pragma unroll
    for (int p = 0; p < 16; ++p) {
        int idx = p * 256 + t;
        int d = idx >> 4, a4 = (idx & 15) * 4;
        float4 v = *(const float4*)(W + d * A_ + a4);
        T[(a4 + 0) * 260 + d] = v.x * scale;
        T[(a4 + 1) * 260 + d] = v.y * scale;
        T[(a4 + 2) * 260 + d] = v.z * scale;
        T[(a4 + 3) * 260 + d] = v.w * scale;
    }
    __syncthreads();
    const int a = t >> 2, d0 = (t & 3) * 64;
    #pragma unroll
    for (int i = 0; i < 16; ++i) {
        float4 v = *(const float4*)(&T[a * 260 + d0 + 4 * i]);
        ushort4 s;
        s.x = f2h_(v.x); s.y = f2h_(v.y); s.z = f2h_(v.z); s.w = f2h_(v.w);
        *(ushort4*)(o + a * D_ + d0 + 4 * i) = s;
    }
}

// ---------------------------------------------------------------------------
// proj: one block per 32 x-rows computes ALL 3 projections. grid (M/32),
// block 384 = 6 waves: wave = (w = wid>>1, mt = wid&1).
// NO x staging: each lane loads its MFMA x-fragments DIRECTLY from global
// ((c,g) lanes tile 128B cache lines exactly; 3 w-waves re-read via L2) and
// converts f32->fp16 in-register. Removes stage loop + 1 barrier + 16.5 KB
// LDS -> pure-stream kernel, higher occupancy.
// q/k fp16 [M][64]; v fp16 TRANSPOSED [B][64][L].
// ---------------------------------------------------------------------------
__global__ __launch_bounds__(384) void proj_kernel(
    const float* __restrict__ x,           // [M][256] f32
    const unsigned short* __restrict__ wt, // [3][64][256] fp16 (W^T)
    unsigned short* __restrict__ qo,
    unsigned short* __restrict__ ko,
    unsigned short* __restrict__ vto)
{
    __shared__ __align__(16) unsigned short Cst[6 * 1536];  // 18 KB
    const int t = threadIdx.x, m0 = blockIdx.x * 32;
    const int wid = t >> 6, lane = t & 63, c = lane & 15, g = lane >> 4;
    const int w = wid >> 1, mt = wid & 1;

    // direct global x fragments: row m0+16mt+c, cols 32s+8g..+7
    const float* xp = x + (size_t)(m0 + 16 * mt + c) * D_;
    half8 xa[8];
    #pragma unroll
    for (int s = 0; s < 8; ++s) {
        float4 v0 = *(const float4*)(xp + 32 * s + 8 * g);
        float4 v1 = *(const float4*)(xp + 32 * s + 8 * g + 4);
        half8 h;
        h[0] = (_Float16)v0.x; h[1] = (_Float16)v0.y;
        h[2] = (_Float16)v0.z; h[3] = (_Float16)v0.w;
        h[4] = (_Float16)v1.x; h[5] = (_Float16)v1.y;
        h[6] = (_Float16)v1.z; h[7] = (_Float16)v1.w;
        xa[s] = h;
    }

    const unsigned short* wsrc = wt + w * A_ * D_;
    unsigned short* Cw = Cst + wid * 1536;
    #pragma unroll
    for (int nt = 0; nt < 4; ++nt) {
        floatx4 acc = {0.f, 0.f, 0.f, 0.f};
        #pragma unroll
        for (int s = 0; s < 8; ++s) {
            half8 wb = *(const half8*)(wsrc + (16 * nt + c) * D_ + 32 * s + 8 * g);
            acc = __builtin_amdgcn_mfma_f32_16x16x32_f16(xa[s], wb, acc, 0, 0, 0);
        }
        // C[m=4g+r][a=16nt+c]
        if (w < 2) {
            #pragma unroll
            for (int r = 0; r < 4; ++r)
                Cw[(4 * g + r) * 72 + 16 * nt + c] = f2h_(acc[r]);      // [m16][72]
        } else {
            #pragma unroll
            for (int r = 0; r < 4; ++r)
                Cw[(16 * nt + c) * 24 + 4 * g + r] = f2h_(acc[r]);      // [a64][24]
        }
    }

    // q/k: wave-local store (wave reads only its own Cst region)
    if (w < 2) {
        unsigned short* o = (w == 0) ? qo : ko;
        const int row16 = lane >> 2, seg = lane & 3;
        uint4 d0 = *(const uint4*)(Cw + row16 * 72 + seg * 16);
        uint4 d1 = *(const uint4*)(Cw + row16 * 72 + seg * 16 + 8);
        unsigned short* p = o + (size_t)(m0 + 16 * mt + row16) * A_ + seg * 16;
        *(uint4*)(p) = d0;
        *(uint4*)(p + 8) = d1;
    }
    __syncthreads();
    // v: combined store from both w=2 waves -> 64B contiguous per a-row
    if (t < 256) {
        const int a = t >> 2, quarter = t & 3;
        const int o = quarter * 8, mtv = o >> 4, idx = o & 15;
        uint4 d = *(const uint4*)(Cst + (4 + mtv) * 1536 + a * 24 + idx);
        const int bb = m0 >> 12, l0 = m0 & (L_ - 1);
        *(uint4*)(vto + ((size_t)(bb * A_ + a)) * L_ + l0 + o) = d;
    }
}

// ---------------------------------------------------------------------------
// attn: split-K flash, 128-q blocks (2 Q-frags/wave), uniform chunks — the
// R6 structure (best measured; R7's gll/dbuf and R8's streaming were
// neutral/regressions). grid (576) 1D, block 512 = 8 waves = 4 qsub x 2 ph.
// ONE change vs R6: partials written as FP16 (halves epilogue + merge
// traffic; values bounded by l*max|v| ~ 2^8, fp16 rel err 5e-4 << tol).
// Decomposition: per batch 32 q-tiles, T = 2qt+2 key tiles, nch = ceil(T/8)
// chunks, 144/batch, big chunks first; x=bx&7 -> XCD, b=x>>1.
// Emits UNNORMALIZED (O fp16, m/l f32) per chunk j: poH[j][M][64], mlB[j][M].
// ---------------------------------------------------------------------------
__global__ __launch_bounds__(512, 4) void attn_kernel(
    const unsigned short* __restrict__ qb,  // [B][L][64] fp16 (x 1/ln2)
    const unsigned short* __restrict__ kb,  // [B][L][64] fp16
    const unsigned short* __restrict__ vt,  // [B][64][L] fp16
    unsigned short* __restrict__ poH,       // [8][M][64] partial O fp16
    float2* __restrict__ mlB)               // [8][M] (m,l)
{
    __shared__ __align__(16) unsigned short smem[4 * 4608];  // 36 KB
    unsigned short* Ks = smem;
    unsigned short* Vs = smem + 2 * 4608;

    const int t    = threadIdx.x;
    const int lane = t & 63;
    const int wid  = t >> 6;          // 0..7
    const int qsub = wid >> 1;        // 0..3 -> 32-row group
    const int ph   = wid & 1;
    const int c    = lane & 15;
    const int g    = lane >> 4;

    // ---- block id -> (b, qt, chunk j of nch) ----
    const int bx = blockIdx.x;
    const int x  = bx & 7, u = bx >> 3;
    const int b  = x >> 1;
    const int gch = 143 - (2 * u + (x & 1));    // reversed: big chunks first
    int m = 0;
    while (2 * (m + 1) * (m + 2) <= gch) ++m;   // uniform scalar, <=7 iters
    const int rem = gch - 2 * m * (m + 1);
    const int nch = m + 1;
    const int qt  = 4 * m + rem / nch;
    const int j   = rem % nch;
    const int T   = 2 * qt + 2;
    const int t0  = (j * T) / nch;
    const int t1  = ((j + 1) * T) / nch;
    const int nIt = (t1 - t0 + 1) >> 1;
    const int Tm2 = T - 2;

    const int q0    = qt * 128;
    const int qrow0 = q0 + 32 * qsub;
    const int qme0  = qrow0 + c;

    const size_t base  = (size_t)b * L_ * A_;
    const size_t vbase = (size_t)b * A_ * L_;

    half8 qf[2][2];
    #pragma unroll
    for (int f = 0; f < 2; ++f) {
        const unsigned short* qp = qb + base + (size_t)(qrow0 + 16 * f + c) * A_ + g * 8;
        qf[f][0] = *(const half8*)(qp);
        qf[f][1] = *(const half8*)(qp + 32);
    }

    floatx4 O4[2][4];
    #pragma unroll
    for (int f = 0; f < 2; ++f)
        #pragma unroll
        for (int at = 0; at < 4; ++at) O4[f][at] = (floatx4){0.f, 0.f, 0.f, 0.f};
    float m_[2] = {-INFINITY, -INFINITY};
    float l_[2] = {0.f, 0.f};

    for (int it = 0; it < nIt; ++it) {
        __syncthreads();
        #pragma unroll
        for (int tile = 0; tile < 2; ++tile) {
            const int kts = t0 + 2 * it + tile;
            if (kts < t1) {
                const int k0s = kts << 6;
                const int row = t >> 3, c8 = t & 7;   // 512 threads cover tile
                uint4 dK = *(const uint4*)(kb + base + (size_t)k0s * 64 + t * 8);
                *(uint4*)(Ks + tile * 4608 + row * 72 + c8 * 8) = dK;
                uint4 dV = *(const uint4*)(vt + vbase + (size_t)row * L_ + k0s + c8 * 8);
                *(uint4*)(Vs + tile * 4608 + row * 72 + c8 * 8) = dV;
            }
        }
        __syncthreads();

        const int kt = t0 + 2 * it + ph;
        if (kt >= t1) continue;          // loop-top barriers stay convergent
        const int k0 = kt << 6;
        const unsigned short* Kw = Ks + ph * 4608;
        const unsigned short* Vw = Vs + ph * 4608;

        half4 pf[2][4];
        #pragma unroll
        for (int f = 0; f < 2; ++f) {
            // ---- S^T = K . Q^T (frag f) ----
            floatx4 S4[4];
            #pragma unroll
            for (int nt = 0; nt < 4; ++nt) S4[nt] = (floatx4){0.f, 0.f, 0.f, 0.f};
            #pragma unroll
            for (int s = 0; s < 2; ++s)
                #pragma unroll
                for (int nt = 0; nt < 4; ++nt) {
                    half8 kf = *(const half8*)(Kw + (16 * nt + c) * 72 + 32 * s + 8 * g);
                    S4[nt] = __builtin_amdgcn_mfma_f32_16x16x32_f16(kf, qf[f][s], S4[nt], 0, 0, 0);
                }

            // ---- causal mask: tiles >= T-2 straddle the 128-q diagonal ----
            if (kt >= Tm2) {
                const int qme = qme0 + 16 * f;
                #pragma unroll
                for (int nt = 0; nt < 4; ++nt)
                    #pragma unroll
                    for (int r = 0; r < 4; ++r)
                        if (k0 + 16 * nt + 4 * g + r > qme) S4[nt][r] = -INFINITY;
            }

            // ---- online softmax (exp2 domain; per-lane q row) ----
            float tm = fmaxf(fmaxf(fmaxf(S4[0][0], S4[0][1]), fmaxf(S4[0][2], S4[0][3])),
                             fmaxf(fmaxf(S4[1][0], S4[1][1]), fmaxf(S4[1][2], S4[1][3])));
            tm = fmaxf(tm, fmaxf(fmaxf(fmaxf(S4[2][0], S4[2][1]), fmaxf(S4[2][2], S4[2][3])),
                                 fmaxf(fmaxf(S4[3][0], S4[3][1]), fmaxf(S4[3][2], S4[3][3]))));
            tm = fmaxf(tm, __shfl_xor(tm, 16));
            tm = fmaxf(tm, __shfl_xor(tm, 32));
            const float mn  = fmaxf(m_[f], tm);
            const float mnc = fmaxf(mn, -3.0e38f);           // guard -inf - -inf
            const float al  = exp2f(fminf(m_[f] - mnc, 0.f)); // m_=-inf -> 0
            float rs = 0.f;
            #pragma unroll
            for (int nt = 0; nt < 4; ++nt) {
                #pragma unroll
                for (int r = 0; r < 4; ++r) {
                    float p = exp2f(S4[nt][r] - mnc);        // masked: exp2(-inf)=0
                    S4[nt][r] = p;
                    rs += p;
                }
                pf[f][nt][0] = (_Float16)S4[nt][0];
                pf[f][nt][1] = (_Float16)S4[nt][1];
                pf[f][nt][2] = (_Float16)S4[nt][2];
                pf[f][nt][3] = (_Float16)S4[nt][3];
            }
            rs += __shfl_xor(rs, 16);
            rs += __shfl_xor(rs, 32);
            l_[f] = l_[f] * al + rs;
            m_[f] = mn;
            #pragma unroll
            for (int at = 0; at < 4; ++at) O4[f][at] *= al;
        }

        // ---- O^T += V^T . P^T: va read once, feeds both frags ----
        #pragma unroll
        for (int at = 0; at < 4; ++at) {
            #pragma unroll
            for (int nt = 0; nt < 4; ++nt) {
                half4 va = *(const half4*)(Vw + (16 * at + c) * 72 + 16 * nt + 4 * g);
                O4[0][at] = __builtin_amdgcn_mfma_f32_16x16x16f16(va, pf[0][nt], O4[0][at], 0, 0, 0);
                O4[1][at] = __builtin_amdgcn_mfma_f32_16x16x16f16(va, pf[1][nt], O4[1][at], 0, 0, 0);
            }
        }
    }

    // ---- epilogue: 2 passes (one per frag), combine ph pairs via LDS ----
    float*  Of  = (float*)smem;                 // [wid][at][lane][r]  32 KB
    float2* mlb = (float2*)(smem + 16384);      // byte off 32768, 1 KB
    #pragma unroll
    for (int f = 0; f < 2; ++f) {
        __syncthreads();
        #pragma unroll
        for (int at = 0; at < 4; ++at) {
            float4 v; v.x = O4[f][at][0]; v.y = O4[f][at][1];
            v.z = O4[f][at][2]; v.w = O4[f][at][3];
            ((float4*)Of)[wid * 256 + at * 64 + lane] = v;
        }
        if (g == 0) { float2 ml; ml.x = m_[f]; ml.y = l_[f]; mlb[wid * 16 + c] = ml; }
        __syncthreads();

        const int q64 = t >> 3, seg = t & 7;
        const int qs = q64 >> 4, cc = q64 & 15;
        const int rowq = 32 * qs + 16 * f + cc;
        const float2 A0 = mlb[(2 * qs) * 16 + cc];
        const float2 A1 = mlb[(2 * qs + 1) * 16 + cc];
        const float mf = fmaxf(A0.x, A1.x);
        const float mc = fmaxf(mf, -3.0e38f);
        const float w0 = exp2f(A0.x - mc);
        const float w1 = exp2f(A1.x - mc);
        const float ls = w0 * A0.y + w1 * A1.y;
        float res[8];
        #pragma unroll
        for (int u2 = 0; u2 < 8; ++u2) {
            const int a = seg * 8 + u2;
            const int at = a >> 4, gg = (a >> 2) & 3, r = a & 3;
            const int i0 = ((2 * qs) * 256 + at * 64 + gg * 16 + cc) * 4 + r;
            const int i1 = ((2 * qs + 1) * 256 + at * 64 + gg * 16 + cc) * 4 + r;
            res[u2] = w0 * Of[i0] + w1 * Of[i1];
        }
        unsigned short* p = poH + (size_t)j * M_ * A_ + base +
                            (size_t)(q0 + rowq) * A_ + seg * 8;
        uint4 d;
        d.x = pack2_(res[0], res[1]);
        d.y = pack2_(res[2], res[3]);
        d.z = pack2_(res[4], res[5]);
        d.w = pack2_(res[6], res[7]);
        *(uint4*)p = d;                          // 8 fp16 = one 16B store
        if (seg == 0) {
            float2 ml; ml.x = mf; ml.y = ls;
            mlB[(size_t)j * M_ + b * L_ + q0 + rowq] = ml;
        }
    }
}

// ---------------------------------------------------------------------------
// merge: final = sum_j(Oj*wj) / sum_j(lj*wj) over nch(qt) chunks, ONLINE,
// statically-unrolled predicated loop (no runtime-indexed array).
// fp16 partials: 8 elements/thread (one half8 load per slot).
// grid (512), block 256.
// ---------------------------------------------------------------------------
__global__ __launch_bounds__(256) void merge_kernel(
    float* __restrict__ out, const unsigned short* __restrict__ poH,
    const float2* __restrict__ mlB)
{
    const int tg = blockIdx.x * 256 + threadIdx.x;   // 131072 half8-groups
    const int q = tg >> 3, s8 = (tg & 7) * 8;
    const int qt = (q & (L_ - 1)) >> 7;              // 128-row q-tiles
    const int nch = (qt + 4) >> 2;                   // ceil((2qt+2)/8)
    float mf = -INFINITY, den = 0.f;
    float a0 = 0.f, a1 = 0.f, a2 = 0.f, a3 = 0.f;
    float a4 = 0.f, a5 = 0.f, a6 = 0.f, a7 = 0.f;
    #pragma unroll
    for (int jj = 0; jj < 8; ++jj) {
        if (jj < nch) {
            const float2 aj = mlB[(size_t)jj * M_ + q];
            const float mn = fmaxf(mf, aj.x);
            const float mc = fmaxf(mn, -3.0e38f);
            const float sc = exp2f(fminf(mf - mc, 0.f));
            const float wj = exp2f(aj.x - mc);
            const half8 o = *(const half8*)(poH + (size_t)jj * M_ * A_ +
                                            (size_t)q * A_ + s8);
            a0 = a0 * sc + (float)o[0] * wj;
            a1 = a1 * sc + (float)o[1] * wj;
            a2 = a2 * sc + (float)o[2] * wj;
            a3 = a3 * sc + (float)o[3] * wj;
            a4 = a4 * sc + (float)o[4] * wj;
            a5 = a5 * sc + (float)o[5] * wj;
            a6 = a6 * sc + (float)o[6] * wj;
            a7 = a7 * sc + (float)o[7] * wj;
            den = den * sc + aj.y * wj;
            mf = mn;
        }
    }
    const float inv = 1.f / den;
    float* p = out + (size_t)q * A_ + s8;
    *(float4*)(p)     = make_float4(a0 * inv, a1 * inv, a2 * inv, a3 * inv);
    *(float4*)(p + 4) = make_float4(a4 * inv, a5 * inv, a6 * inv, a7 * inv);
}

// ---------------------------------------------------------------------------
extern "C" void kernel_launch(void* const* d_in, const int* in_sizes, int n_in,
                              void* d_out, int out_size, void* d_ws, size_t ws_size,
                              hipStream_t stream) {
    const float* x  = (const float*)d_in[0];
    const float* Wq = (const float*)d_in[1];
    const float* Wk = (const float*)d_in[2];
    const float* Wv = (const float*)d_in[3];

    char* ws = (char*)d_ws;
    unsigned short* qb = (unsigned short*)(ws);                    // 2 MB
    unsigned short* kb = (unsigned short*)(ws + (2u << 20));       // 2 MB
    unsigned short* vt = (unsigned short*)(ws + (4u << 20));       // 2 MB
    unsigned short* wt = (unsigned short*)(ws + (6u << 20));       // 96 KB (128 KB reserved)
    char* p0 = ws + (6u << 20) + (128u << 10);
    unsigned short* poH = (unsigned short*)(p0);                   // 8 x 2 MB fp16
    float2* mlB = (float2*)(p0 + (16u << 20));                     // 8 x 128 KB
    float* out = (float*)d_out;

    hipLaunchKernelGGL(wconv_kernel, dim3(3), dim3(256), 0, stream, Wq, Wk, Wv, wt);
    hipLaunchKernelGGL(proj_kernel, dim3(M_ / 32), dim3(384), 0, stream, x, wt, qb, kb, vt);
    hipLaunchKernelGGL(attn_kernel, dim3(576), dim3(512), 0, stream,
                       qb, kb, vt, poH, mlB);
    hipLaunchKernelGGL(merge_kernel, dim3(512), dim3(256), 0, stream,
                       out, poH, mlB);
}

// Round 10
// 121.648 us; speedup vs baseline: 1.7998x; 1.0287x over previous
//
#include <hip/hip_runtime.h>
#include <math.h>

#define B_ 4
#define L_ 4096
#define D_ 256
#define A_ 64
#define M_ (B_*L_)   // 16384 flat rows

typedef _Float16 half4 __attribute__((ext_vector_type(4)));
typedef _Float16 half8 __attribute__((ext_vector_type(8)));
typedef __attribute__((ext_vector_type(4))) float floatx4;

__device__ __forceinline__ unsigned short f2h_(float f) {
    _Float16 h = (_Float16)f;
    return __builtin_bit_cast(unsigned short, h);
}
__device__ __forceinline__ unsigned int pack2_(float a, float b) {
    return (unsigned int)f2h_(a) | ((unsigned int)f2h_(b) << 16);
}

// ---------------------------------------------------------------------------
// wconv: W f32 [256][64] -> W^T fp16 [64][256]. Wq scaled by 1/ln2 (exp2
// softmax domain). grid (3), block 256.
// ---------------------------------------------------------------------------
__global__ __launch_bounds__(256) void wconv_kernel(
    const float* __restrict__ Wq, const float* __restrict__ Wk,
    const float* __restrict__ Wv, unsigned short* __restrict__ wt)
{
    const int w = blockIdx.x, t = threadIdx.x;
    const float* W = (w == 0) ? Wq : (w == 1) ? Wk : Wv;
    unsigned short* o = wt + w * A_ * D_;
    const float scale = (w == 0) ? 1.44269504f : 1.0f;
    __shared__ float T[A_ * 260];
    #pragma unroll
    for (int p = 0; p < 16; ++p) {
        int idx = p * 256 + t;
        int d = idx >> 4, a4 = (idx & 15) * 4;
        float4 v = *(const float4*)(W + d * A_ + a4);
        T[(a4 + 0) * 260 + d] = v.x * scale;
        T[(a4 + 1) * 260 + d] = v.y * scale;
        T[(a4 + 2) * 260 + d] = v.z * scale;
        T[(a4 + 3) * 260 + d] = v.w * scale;
    }
    __syncthreads();
    const int a = t >> 2, d0 = (t & 3) * 64;
    #pragma unroll
    for (int i = 0; i < 16; ++i) {
        float4 v = *(const float4*)(&T[a * 260 + d0 + 4 * i]);
        ushort4 s;
        s.x = f2h_(v.x); s.y = f2h_(v.y); s.z = f2h_(v.z); s.w = f2h_(v.w);
        *(ushort4*)(o + a * D_ + d0 + 4 * i) = s;
    }
}

// ---------------------------------------------------------------------------
// proj: one block per 32 x-rows computes ALL 3 projections (x staged once —
// R9's destaged variant regressed via 3x L2 re-read; staging restored).
// grid (M/32), block 384 = 6 waves: wave = (w = wid>>1, mt = wid&1).
// q/k fp16 [M][64]; v fp16 TRANSPOSED [B][64][L].
// ---------------------------------------------------------------------------
__global__ __launch_bounds__(384) void proj_kernel(
    const float* __restrict__ x,           // [M][256] f32
    const unsigned short* __restrict__ wt, // [3][64][256] fp16 (W^T)
    unsigned short* __restrict__ qo,
    unsigned short* __restrict__ ko,
    unsigned short* __restrict__ vto)
{
    __shared__ __align__(16) unsigned short Xh[32 * 264];   // 16.5 KB
    __shared__ __align__(16) unsigned short Cst[6 * 1536];  // 18 KB
    const int t = threadIdx.x, m0 = blockIdx.x * 32;

    #pragma unroll
    for (int p = 0; p < 6; ++p) {
        int idx = p * 384 + t;
        if (idx < 2048) {
            int row = idx >> 6, col = (idx & 63) * 4;
            float4 v = *(const float4*)(x + (size_t)(m0 + row) * D_ + col);
            ushort4 s;
            s.x = f2h_(v.x); s.y = f2h_(v.y); s.z = f2h_(v.z); s.w = f2h_(v.w);
            *(ushort4*)(Xh + row * 264 + col) = s;
        }
    }
    __syncthreads();

    const int wid = t >> 6, lane = t & 63, c = lane & 15, g = lane >> 4;
    const int w = wid >> 1, mt = wid & 1;

    half8 xa[8];
    #pragma unroll
    for (int s = 0; s < 8; ++s)
        xa[s] = *(const half8*)(Xh + (16 * mt + c) * 264 + 32 * s + 8 * g);

    const unsigned short* wsrc = wt + w * A_ * D_;
    unsigned short* Cw = Cst + wid * 1536;
    #pragma unroll
    for (int nt = 0; nt < 4; ++nt) {
        floatx4 acc = {0.f, 0.f, 0.f, 0.f};
        #pragma unroll
        for (int s = 0; s < 8; ++s) {
            half8 wb = *(const half8*)(wsrc + (16 * nt + c) * D_ + 32 * s + 8 * g);
            acc = __builtin_amdgcn_mfma_f32_16x16x32_f16(xa[s], wb, acc, 0, 0, 0);
        }
        // C[m=4g+r][a=16nt+c]
        if (w < 2) {
            #pragma unroll
            for (int r = 0; r < 4; ++r)
                Cw[(4 * g + r) * 72 + 16 * nt + c] = f2h_(acc[r]);      // [m16][72]
        } else {
            #pragma unroll
            for (int r = 0; r < 4; ++r)
                Cw[(16 * nt + c) * 24 + 4 * g + r] = f2h_(acc[r]);      // [a64][24]
        }
    }

    // q/k: wave-local store (wave reads only its own Cst region)
    if (w < 2) {
        unsigned short* o = (w == 0) ? qo : ko;
        const int row16 = lane >> 2, seg = lane & 3;
        uint4 d0 = *(const uint4*)(Cw + row16 * 72 + seg * 16);
        uint4 d1 = *(const uint4*)(Cw + row16 * 72 + seg * 16 + 8);
        unsigned short* p = o + (size_t)(m0 + 16 * mt + row16) * A_ + seg * 16;
        *(uint4*)(p) = d0;
        *(uint4*)(p + 8) = d1;
    }
    __syncthreads();
    // v: combined store from both w=2 waves -> 64B contiguous per a-row
    if (t < 256) {
        const int a = t >> 2, quarter = t & 3;
        const int o = quarter * 8, mtv = o >> 4, idx = o & 15;
        uint4 d = *(const uint4*)(Cst + (4 + mtv) * 1536 + a * 24 + idx);
        const int bb = m0 >> 12, l0 = m0 & (L_ - 1);
        *(uint4*)(vto + ((size_t)(bb * A_ + a)) * L_ + l0 + o) = d;
    }
}

// ---------------------------------------------------------------------------
// attn: R6 structure exactly (best measured: 123.57) — split-K flash, 128-q
// blocks (2 Q-frags/wave), uniform ~8-tile chunks, sync LDS staging with
// padded-72 layout. grid (576) 1D, block 512 = 8 waves = 4 qsub x 2 ph.
// ONLY change vs R6: partials written FP16 (halves epilogue+merge traffic;
// values bounded ~2^8, fp16 rel err 5e-4 << tol 0.03).
// Decomposition: per batch 32 q-tiles, T = 2qt+2 key tiles, nch = ceil(T/8)
// chunks, 144/batch, big chunks first; x=bx&7 -> XCD, b=x>>1.
// Emits UNNORMALIZED (O fp16, m/l f32) per chunk j: poH[j][M][64], mlB[j][M].
// ---------------------------------------------------------------------------
__global__ __launch_bounds__(512, 4) void attn_kernel(
    const unsigned short* __restrict__ qb,  // [B][L][64] fp16 (x 1/ln2)
    const unsigned short* __restrict__ kb,  // [B][L][64] fp16
    const unsigned short* __restrict__ vt,  // [B][64][L] fp16
    unsigned short* __restrict__ poH,       // [8][M][64] partial O fp16
    float2* __restrict__ mlB)               // [8][M] (m,l)
{
    __shared__ __align__(16) unsigned short smem[4 * 4608];  // 36 KB
    unsigned short* Ks = smem;
    unsigned short* Vs = smem + 2 * 4608;

    const int t    = threadIdx.x;
    const int lane = t & 63;
    const int wid  = t >> 6;          // 0..7
    const int qsub = wid >> 1;        // 0..3 -> 32-row group
    const int ph   = wid & 1;
    const int c    = lane & 15;
    const int g    = lane >> 4;

    // ---- block id -> (b, qt, chunk j of nch) ----
    const int bx = blockIdx.x;
    const int x  = bx & 7, u = bx >> 3;
    const int b  = x >> 1;
    const int gch = 143 - (2 * u + (x & 1));    // reversed: big chunks first
    int m = 0;
    while (2 * (m + 1) * (m + 2) <= gch) ++m;   // uniform scalar, <=7 iters
    const int rem = gch - 2 * m * (m + 1);
    const int nch = m + 1;
    const int qt  = 4 * m + rem / nch;
    const int j   = rem % nch;
    const int T   = 2 * qt + 2;
    const int t0  = (j * T) / nch;
    const int t1  = ((j + 1) * T) / nch;
    const int nIt = (t1 - t0 + 1) >> 1;
    const int Tm2 = T - 2;

    const int q0    = qt * 128;
    const int qrow0 = q0 + 32 * qsub;
    const int qme0  = qrow0 + c;

    const size_t base  = (size_t)b * L_ * A_;
    const size_t vbase = (size_t)b * A_ * L_;

    half8 qf[2][2];
    #pragma unroll
    for (int f = 0; f < 2; ++f) {
        const unsigned short* qp = qb + base + (size_t)(qrow0 + 16 * f + c) * A_ + g * 8;
        qf[f][0] = *(const half8*)(qp);
        qf[f][1] = *(const half8*)(qp + 32);
    }

    floatx4 O4[2][4];
    #pragma unroll
    for (int f = 0; f < 2; ++f)
        #pragma unroll
        for (int at = 0; at < 4; ++at) O4[f][at] = (floatx4){0.f, 0.f, 0.f, 0.f};
    float m_[2] = {-INFINITY, -INFINITY};
    float l_[2] = {0.f, 0.f};

    for (int it = 0; it < nIt; ++it) {
        __syncthreads();
        #pragma unroll
        for (int tile = 0; tile < 2; ++tile) {
            const int kts = t0 + 2 * it + tile;
            if (kts < t1) {
                const int k0s = kts << 6;
                const int row = t >> 3, c8 = t & 7;   // 512 threads cover tile
                uint4 dK = *(const uint4*)(kb + base + (size_t)k0s * 64 + t * 8);
                *(uint4*)(Ks + tile * 4608 + row * 72 + c8 * 8) = dK;
                uint4 dV = *(const uint4*)(vt + vbase + (size_t)row * L_ + k0s + c8 * 8);
                *(uint4*)(Vs + tile * 4608 + row * 72 + c8 * 8) = dV;
            }
        }
        __syncthreads();

        const int kt = t0 + 2 * it + ph;
        if (kt >= t1) continue;          // loop-top barriers stay convergent
        const int k0 = kt << 6;
        const unsigned short* Kw = Ks + ph * 4608;
        const unsigned short* Vw = Vs + ph * 4608;

        half4 pf[2][4];
        #pragma unroll
        for (int f = 0; f < 2; ++f) {
            // ---- S^T = K . Q^T (frag f) ----
            floatx4 S4[4];
            #pragma unroll
            for (int nt = 0; nt < 4; ++nt) S4[nt] = (floatx4){0.f, 0.f, 0.f, 0.f};
            #pragma unroll
            for (int s = 0; s < 2; ++s)
                #pragma unroll
                for (int nt = 0; nt < 4; ++nt) {
                    half8 kf = *(const half8*)(Kw + (16 * nt + c) * 72 + 32 * s + 8 * g);
                    S4[nt] = __builtin_amdgcn_mfma_f32_16x16x32_f16(kf, qf[f][s], S4[nt], 0, 0, 0);
                }

            // ---- causal mask: tiles >= T-2 straddle the 128-q diagonal ----
            if (kt >= Tm2) {
                const int qme = qme0 + 16 * f;
                #pragma unroll
                for (int nt = 0; nt < 4; ++nt)
                    #pragma unroll
                    for (int r = 0; r < 4; ++r)
                        if (k0 + 16 * nt + 4 * g + r > qme) S4[nt][r] = -INFINITY;
            }

            // ---- online softmax (exp2 domain; per-lane q row) ----
            float tm = fmaxf(fmaxf(fmaxf(S4[0][0], S4[0][1]), fmaxf(S4[0][2], S4[0][3])),
                             fmaxf(fmaxf(S4[1][0], S4[1][1]), fmaxf(S4[1][2], S4[1][3])));
            tm = fmaxf(tm, fmaxf(fmaxf(fmaxf(S4[2][0], S4[2][1]), fmaxf(S4[2][2], S4[2][3])),
                                 fmaxf(fmaxf(S4[3][0], S4[3][1]), fmaxf(S4[3][2], S4[3][3]))));
            tm = fmaxf(tm, __shfl_xor(tm, 16));
            tm = fmaxf(tm, __shfl_xor(tm, 32));
            const float mn  = fmaxf(m_[f], tm);
            const float mnc = fmaxf(mn, -3.0e38f);           // guard -inf - -inf
            const float al  = exp2f(fminf(m_[f] - mnc, 0.f)); // m_=-inf -> 0
            float rs = 0.f;
            #pragma unroll
            for (int nt = 0; nt < 4; ++nt) {
                #pragma unroll
                for (int r = 0; r < 4; ++r) {
                    float p = exp2f(S4[nt][r] - mnc);        // masked: exp2(-inf)=0
                    S4[nt][r] = p;
                    rs += p;
                }
                pf[f][nt][0] = (_Float16)S4[nt][0];
                pf[f][nt][1] = (_Float16)S4[nt][1];
                pf[f][nt][2] = (_Float16)S4[nt][2];
                pf[f][nt][3] = (_Float16)S4[nt][3];
            }
            rs += __shfl_xor(rs, 16);
            rs += __shfl_xor(rs, 32);
            l_[f] = l_[f] * al + rs;
            m_[f] = mn;
            #pragma unroll
            for (int at = 0; at < 4; ++at) O4[f][at] *= al;
        }

        // ---- O^T += V^T . P^T: va read once, feeds both frags ----
        #pragma unroll
        for (int at = 0; at < 4; ++at) {
            #pragma unroll
            for (int nt = 0; nt < 4; ++nt) {
                half4 va = *(const half4*)(Vw + (16 * at + c) * 72 + 16 * nt + 4 * g);
                O4[0][at] = __builtin_amdgcn_mfma_f32_16x16x16f16(va, pf[0][nt], O4[0][at], 0, 0, 0);
                O4[1][at] = __builtin_amdgcn_mfma_f32_16x16x16f16(va, pf[1][nt], O4[1][at], 0, 0, 0);
            }
        }
    }

    // ---- epilogue: 2 passes (one per frag), combine ph pairs via LDS ----
    float*  Of  = (float*)smem;                 // [wid][at][lane][r]  32 KB
    float2* mlb = (float2*)(smem + 16384);      // byte off 32768, 1 KB
    #pragma unroll
    for (int f = 0; f < 2; ++f) {
        __syncthreads();
        #pragma unroll
        for (int at = 0; at < 4; ++at) {
            float4 v; v.x = O4[f][at][0]; v.y = O4[f][at][1];
            v.z = O4[f][at][2]; v.w = O4[f][at][3];
            ((float4*)Of)[wid * 256 + at * 64 + lane] = v;
        }
        if (g == 0) { float2 ml; ml.x = m_[f]; ml.y = l_[f]; mlb[wid * 16 + c] = ml; }
        __syncthreads();

        const int q64 = t >> 3, seg = t & 7;
        const int qs = q64 >> 4, cc = q64 & 15;
        const int rowq = 32 * qs + 16 * f + cc;
        const float2 A0 = mlb[(2 * qs) * 16 + cc];
        const float2 A1 = mlb[(2 * qs + 1) * 16 + cc];
        const float mf = fmaxf(A0.x, A1.x);
        const float mc = fmaxf(mf, -3.0e38f);
        const float w0 = exp2f(A0.x - mc);
        const float w1 = exp2f(A1.x - mc);
        const float ls = w0 * A0.y + w1 * A1.y;
        float res[8];
        #pragma unroll
        for (int u2 = 0; u2 < 8; ++u2) {
            const int a = seg * 8 + u2;
            const int at = a >> 4, gg = (a >> 2) & 3, r = a & 3;
            const int i0 = ((2 * qs) * 256 + at * 64 + gg * 16 + cc) * 4 + r;
            const int i1 = ((2 * qs + 1) * 256 + at * 64 + gg * 16 + cc) * 4 + r;
            res[u2] = w0 * Of[i0] + w1 * Of[i1];
        }
        unsigned short* p = poH + (size_t)j * M_ * A_ + base +
                            (size_t)(q0 + rowq) * A_ + seg * 8;
        uint4 d;
        d.x = pack2_(res[0], res[1]);
        d.y = pack2_(res[2], res[3]);
        d.z = pack2_(res[4], res[5]);
        d.w = pack2_(res[6], res[7]);
        *(uint4*)p = d;                          // 8 fp16 = one 16B store
        if (seg == 0) {
            float2 ml; ml.x = mf; ml.y = ls;
            mlB[(size_t)j * M_ + b * L_ + q0 + rowq] = ml;
        }
    }
}

// ---------------------------------------------------------------------------
// merge: final = sum_j(Oj*wj) / sum_j(lj*wj) over nch(qt) chunks, ONLINE,
// statically-unrolled predicated loop (no runtime-indexed array).
// fp16 partials: 8 elements/thread (one half8 load per slot).
// grid (512), block 256.
// ---------------------------------------------------------------------------
__global__ __launch_bounds__(256) void merge_kernel(
    float* __restrict__ out, const unsigned short* __restrict__ poH,
    const float2* __restrict__ mlB)
{
    const int tg = blockIdx.x * 256 + threadIdx.x;   // 131072 half8-groups
    const int q = tg >> 3, s8 = (tg & 7) * 8;
    const int qt = (q & (L_ - 1)) >> 7;              // 128-row q-tiles
    const int nch = (qt + 4) >> 2;                   // ceil((2qt+2)/8)
    float mf = -INFINITY, den = 0.f;
    float a0 = 0.f, a1 = 0.f, a2 = 0.f, a3 = 0.f;
    float a4 = 0.f, a5 = 0.f, a6 = 0.f, a7 = 0.f;
    #pragma unroll
    for (int jj = 0; jj < 8; ++jj) {
        if (jj < nch) {
            const float2 aj = mlB[(size_t)jj * M_ + q];
            const float mn = fmaxf(mf, aj.x);
            const float mc = fmaxf(mn, -3.0e38f);
            const float sc = exp2f(fminf(mf - mc, 0.f));
            const float wj = exp2f(aj.x - mc);
            const half8 o = *(const half8*)(poH + (size_t)jj * M_ * A_ +
                                            (size_t)q * A_ + s8);
            a0 = a0 * sc + (float)o[0] * wj;
            a1 = a1 * sc + (float)o[1] * wj;
            a2 = a2 * sc + (float)o[2] * wj;
            a3 = a3 * sc + (float)o[3] * wj;
            a4 = a4 * sc + (float)o[4] * wj;
            a5 = a5 * sc + (float)o[5] * wj;
            a6 = a6 * sc + (float)o[6] * wj;
            a7 = a7 * sc + (float)o[7] * wj;
            den = den * sc + aj.y * wj;
            mf = mn;
        }
    }
    const float inv = 1.f / den;
    float* p = out + (size_t)q * A_ + s8;
    *(float4*)(p)     = make_float4(a0 * inv, a1 * inv, a2 * inv, a3 * inv);
    *(float4*)(p + 4) = make_float4(a4 * inv, a5 * inv, a6 * inv, a7 * inv);
}

// ---------------------------------------------------------------------------
extern "C" void kernel_launch(void* const* d_in, const int* in_sizes, int n_in,
                              void* d_out, int out_size, void* d_ws, size_t ws_size,
                              hipStream_t stream) {
    const float* x  = (const float*)d_in[0];
    const float* Wq = (const float*)d_in[1];
    const float* Wk = (const float*)d_in[2];
    const float* Wv = (const float*)d_in[3];

    char* ws = (char*)d_ws;
    unsigned short* qb = (unsigned short*)(ws);                    // 2 MB
    unsigned short* kb = (unsigned short*)(ws + (2u << 20));       // 2 MB
    unsigned short* vt = (unsigned short*)(ws + (4u << 20));       // 2 MB
    unsigned short* wt = (unsigned short*)(ws + (6u << 20));       // 96 KB (128 KB reserved)
    char* p0 = ws + (6u << 20) + (128u << 10);
    unsigned short* poH = (unsigned short*)(p0);                   // 8 x 2 MB fp16
    float2* mlB = (float2*)(p0 + (16u << 20));                     // 8 x 128 KB
    float* out = (float*)d_out;

    hipLaunchKernelGGL(wconv_kernel, dim3(3), dim3(256), 0, stream, Wq, Wk, Wv, wt);
    hipLaunchKernelGGL(proj_kernel, dim3(M_ / 32), dim3(384), 0, stream, x, wt, qb, kb, vt);
    hipLaunchKernelGGL(attn_kernel, dim3(576), dim3(512), 0, stream,
                       qb, kb, vt, poH, mlB);
    hipLaunchKernelGGL(merge_kernel, dim3(512), dim3(256), 0, stream,
                       out, poH, mlB);
}